// Round 7
// baseline (744.018 us; speedup 1.0000x reference)
//
#include <hip/hip_runtime.h>
#include <hip/hip_bf16.h>

typedef unsigned short u16;
typedef unsigned char  u8;
typedef __attribute__((ext_vector_type(4))) float floatx4;  // MFMA C/D frag

#define LN_EPS 1e-5f

__device__ __forceinline__ float bf2f(u16 u) {
    unsigned int i = ((unsigned int)u) << 16;
    float f; __builtin_memcpy(&f, &i, 4); return f;
}
__device__ __forceinline__ u16 f2bf(float f) {
    __hip_bfloat16 h = __float2bfloat16(f);   // RNE
    u16 u; __builtin_memcpy(&u, &h, 2); return u;
}
// f32 -> OCP e4m3fn via HW packed convert (self-consistent with fp8 MFMA)
__device__ __forceinline__ u8 f2e4(float f) {
    int p = __builtin_amdgcn_cvt_pk_fp8_f32(f, f, 0, false);
    return (u8)(p & 0xff);
}

// GEMM-operand global pre-swizzle: row m stores k-byte at window(k) + slot-perm:
//   phys(m, k) = (k & ~63) | (((k>>3) + (m>>1)) & 7)*8 | (k & 7)
// -> LDS staging is a verbatim linear row copy; ds_read_b64 at slot (s + (row>>1))&7
//    puts a 16-lane quarter-group on all 32 banks exactly once (zero conflicts).
__device__ __forceinline__ int swz(int m, int k) {
    return (k & ~63) | (((((k >> 3) + (m >> 1)) & 7) << 3)) | (k & 7);
}

// async global->LDS, 16 B per lane; lds dest must be wave-uniform (HW adds lane*16)
__device__ __forceinline__ void gl_lds16(const u8* g, u8* l) {
    __builtin_amdgcn_global_load_lds(
        (const __attribute__((address_space(1))) void*)(const void*)g,
        (__attribute__((address_space(3))) void*)(void*)l,
        16, 0, 0);
}

// ---------------------------------------------------------------- f32 -> fp8 e4m3 (weights, pre-swizzled rows)
__global__ void cvt_f2e4_kernel(const float* __restrict__ in, u8* __restrict__ out,
                                int n4, int Kp) {
    int i = blockIdx.x * blockDim.x + threadIdx.x;
    if (i < n4) {
        float4 f = ((const float4*)in)[i];
        uchar4 o; o.x = f2e4(f.x); o.y = f2e4(f.y); o.z = f2e4(f.z); o.w = f2e4(f.w);
        int e = i * 4;
        int n = e / Kp, k = e - n * Kp;          // 4 bytes stay inside one 8-B slot (k&7 in {0,4})
        *(uchar4*)(out + (size_t)n * Kp + swz(n, k)) = o;
    }
}

__global__ void zero_kernel(u16* __restrict__ p, int n) {
    int i = blockIdx.x * blockDim.x + threadIdx.x;
    if (i < n) p[i] = 0;
}

__global__ void zero_f32_kernel(float* __restrict__ p, int n) {
    int i = blockIdx.x * blockDim.x + threadIdx.x;
    if (i < n) p[i] = 0.f;
}

// ---------------------------------------------------------------- LayerNorm over C=384 -> fp8 (pre-swizzled rows)
__global__ __launch_bounds__(64)
void ln_kernel(const float* __restrict__ xf, const float* __restrict__ g,
               const float* __restrict__ b, u8* __restrict__ out) {
    const int row = blockIdx.x;
    const int lane = threadIdx.x;
    const float* xr = xf + (size_t)row * 384;
    float v[6], s = 0.f, s2 = 0.f;
#pragma unroll
    for (int i = 0; i < 6; ++i) { v[i] = xr[lane + i * 64]; s += v[i]; s2 += v[i] * v[i]; }
#pragma unroll
    for (int off = 32; off; off >>= 1) { s += __shfl_xor(s, off); s2 += __shfl_xor(s2, off); }
    float mean = s * (1.0f / 384.0f);
    float var  = s2 * (1.0f / 384.0f) - mean * mean;
    float rstd = rsqrtf(var + LN_EPS);
    u8* orow = out + (size_t)row * 384;
    const int gperm = (row >> 1) & 7;
    const int pofs = ((((lane >> 3) + gperm) & 7) << 3) | (lane & 7);
#pragma unroll
    for (int i = 0; i < 6; ++i) {
        int c = lane + i * 64;
        orow[i * 64 + pofs] = f2e4((v[i] - mean) * rstd * g[c] + b[c]);
    }
}

// ---------------------------------------------------------------- MFMA NT GEMM (fp8 e4m3 A,B): C = A[M,K] * B[N,K]^T
// 128x128 tile, BK=64, 256 thr / 4 waves (64x64/wave), dbuf LDS 32 KB -> 4 blk/CU.
// Operands are GLOBALLY pre-swizzled (see swz): staging = linear verbatim copy;
// ds_read_b64 slot = (kh*4 + klane + (row>>1)) & 7 -> quarter-group covers all 32 banks
// once = ZERO bank conflicts (fixes r6's 1.19e7 residual from the 4-position rotation).
// Conv A rows are shifted (C = m0+48dy+dx per tap): wave-uniform slot base (C>>1)&7 with
// parity-selected lane half (fr>>1 vs (fr+1)>>1), recomputed once per tap on the read side.
// Sync = r2's proven minimal loop: {mfma; lgkm0; bar; STAGE(t+2); counted vmcnt(4); bar}.
// ACONV: 0 plain A[M,K]; 1 implicit im2col (H=W=48, K=3456).
// EPI: 0 bf16 store; 1 BN+GELU->fp8 (pre-swizzled); 2 BN -> xf += gamma*v; 3 xf += gamma*v;
//      4 ofb = xf + gamma*v; 5 xf = xin + gamma*v
template<int ACONV, int EPI>
__global__ __launch_bounds__(256, 4)
void gemm_nt(const u8* __restrict__ A, const u8* __restrict__ Bm,
             int M, int N, int K,
             u16* __restrict__ Obf, int ldo,
             float* __restrict__ xf, float* __restrict__ ofb, const float* __restrict__ xin,
             const float* __restrict__ bn_g, const float* __restrict__ bn_b,
             const float* __restrict__ bn_m, const float* __restrict__ bn_v,
             const float* __restrict__ gamma, const u8* __restrict__ zp) {
    __shared__ u8 As[2][128 * 64];
    __shared__ u8 Bs[2][128 * 64];

    const int tid = threadIdx.x;
    // XCD swizzle: L = (g%8)*(G/8) + g/8 ; n_tile = L % gx (fast), m_tile = L / gx
    const int gx = gridDim.x;
    const int g  = blockIdx.y * gx + blockIdx.x;
    const int G  = gx * gridDim.y;
    int L = g;
    if ((G & 7) == 0) L = (g & 7) * (G >> 3) + (g >> 3);
    const int n0 = (L % gx) * 128;
    const int m0 = (L / gx) * 128;

    const int lane  = tid & 63;
    const int wave  = tid >> 6;
    const int wm    = (wave >> 1) * 64;
    const int wn    = (wave & 1) * 64;
    const int fr    = lane & 15;
    const int klane = lane >> 4;

    const int hE = fr >> 1;
    const int hO = ((fr + 1) >> 1) & 7;

    int arow[4], brow[4];
#pragma unroll
    for (int i = 0; i < 4; ++i) {
        arow[i] = (wm + i * 16 + fr) * 64;
        brow[i] = (wn + i * 16 + fr) * 64;
    }
    // plain rows: base row multiple of 128 -> perm base 0; slot = (kh*4 + klane + fr>>1)&7
    int csw[2];
#pragma unroll
    for (int kh = 0; kh < 2; ++kh)
        csw[kh] = ((((kh << 2) + klane) + hE) & 7) << 3;
    int cswA[2] = { csw[0], csw[1] };            // conv A: per-tap override

    // staging: verbatim linear copy; thread stages 16 B at row (q*64 + tid>>2), col (tid&3)*16
    const int srow = tid >> 2;
    const int scol = (tid & 3) << 4;
    const u8 *sa[2], *sb[2];
    const u8* imgq[2];
    int ay[2], ax[2];
#pragma unroll
    for (int q = 0; q < 2; ++q) {
        int r = q * 64 + srow;
        if (ACONV == 0) {
            sa[q] = A + (size_t)(m0 + r) * K + scol;
        } else {
            int nA = m0 + r;
            int bi = nA / 2304;                  // 128-tile never crosses image (128 | 2304)
            int nl = nA - bi * 2304;
            ay[q] = nl / 48;
            ax[q] = nl - ay[q] * 48;
            imgq[q] = A + (size_t)bi * 2304 * 384;
        }
        sb[q] = Bm + (size_t)(n0 + q * 64 + srow) * K + scol;
    }

    int scnt = 0, sjj = 0;
    const int NT = K / 64;

    auto STAGE = [&](int d) {
        if (ACONV == 1) {
            if (scnt == 0) {                     // new 3x3 tap: recompute A pointers
                int t3 = sjj / 3;
                int dy = t3 - 1, dx = sjj - t3 * 3 - 1;
                ++sjj;
#pragma unroll
                for (int q = 0; q < 2; ++q) {
                    int yy = ay[q] + dy, xx = ax[q] + dx;
                    bool v = ((unsigned)yy < 48u) & ((unsigned)xx < 48u);
                    sa[q] = (v ? imgq[q] + (size_t)(yy * 48 + xx) * 384 : zp) + scol;
                }
            }
            scnt = (scnt == 5) ? 0 : scnt + 1;
        }
        u8* la = &As[d][0];
        u8* lb = &Bs[d][0];
        gl_lds16(sa[0], la + ((wave * 64) << 4));        sa[0] += 64;
        gl_lds16(sa[1], la + ((256 + wave * 64) << 4));  sa[1] += 64;
        gl_lds16(sb[0], lb + ((wave * 64) << 4));        sb[0] += 64;
        gl_lds16(sb[1], lb + ((256 + wave * 64) << 4));  sb[1] += 64;
    };

    floatx4 acc[4][4];
#pragma unroll
    for (int i = 0; i < 4; ++i)
#pragma unroll
        for (int j = 0; j < 4; ++j) acc[i][j] = (floatx4){0.f, 0.f, 0.f, 0.f};

    // prologue: tiles 0,1 in flight (4 loads each per thread); counted wait on tile 0 only
    STAGE(0);
    STAGE(1);
    asm volatile("s_waitcnt vmcnt(4)" ::: "memory");
    __builtin_amdgcn_s_barrier();
    asm volatile("" ::: "memory");

    int rcnt = 0, rtap = 0;                      // read-side tap tracker (conv)
    int cur = 0;
    for (int t = 0; t < NT; ++t) {
        if (ACONV == 1) {
            if (rcnt == 0) {                     // read-side per-tap slot base
                int t3 = rtap / 3;
                int dy = t3 - 1, dx = rtap - t3 * 3 - 1;
                ++rtap;
                int Cp = m0 + dy * 48 + dx + 4608;      // keep positive; +4608 preserves (>>1)&7
                int cc = (Cp >> 1) & 7;
                int h  = (Cp & 1) ? hO : hE;
                cswA[0] = ((klane + h + cc) & 7) << 3;
                cswA[1] = ((4 + klane + h + cc) & 7) << 3;
            }
            rcnt = (rcnt == 5) ? 0 : rcnt + 1;
        }
        const u8* Ab = &As[cur][0];
        const u8* Bb = &Bs[cur][0];
#pragma unroll
        for (int kh = 0; kh < 2; ++kh) {
            long af[4], bfr[4];
#pragma unroll
            for (int i = 0; i < 4; ++i) af[i]  = *(const long*)(Ab + arow[i] + (ACONV ? cswA[kh] : csw[kh]));
#pragma unroll
            for (int j = 0; j < 4; ++j)  bfr[j] = *(const long*)(Bb + brow[j] + csw[kh]);
#pragma unroll
            for (int i = 0; i < 4; ++i)
#pragma unroll
                for (int j = 0; j < 4; ++j)
                    acc[i][j] = __builtin_amdgcn_mfma_f32_16x16x32_fp8_fp8(af[i], bfr[j], acc[i][j], 0, 0, 0);
        }
        asm volatile("s_waitcnt lgkmcnt(0)" ::: "memory");   // this wave's reads of buf[cur] done
        __builtin_amdgcn_s_barrier();                        // all waves done -> buf[cur] free
        asm volatile("" ::: "memory");
        if (t + 2 < NT) {
            STAGE(cur);                                      // issue tile t+2 into freed buffer
            asm volatile("s_waitcnt vmcnt(4)" ::: "memory"); // drain tile t+1 (issued 1 tile ago)
        } else {
            asm volatile("s_waitcnt vmcnt(0)" ::: "memory"); // tail: nothing new issued
        }
        __builtin_amdgcn_sched_barrier(0);
        __builtin_amdgcn_s_barrier();                        // tile t+1 resident for all waves
        asm volatile("" ::: "memory");
        cur ^= 1;
    }

    // Epilogue. C/D layout: col = lane&15, row = (lane>>4)*4 + reg  [dtype-independent, m121-128]
    const int quad4 = (lane >> 4) * 4;
#pragma unroll
    for (int j = 0; j < 4; ++j) {
        int col = n0 + wn + j * 16 + fr;
        float bscale = 0.f, bshift = 0.f, gam = 0.f;
        if (EPI == 1 || EPI == 2) {
            bscale = bn_g[col] * rsqrtf(bn_v[col] + LN_EPS);
            bshift = bn_b[col] - bn_m[col] * bscale;
        }
        if (EPI >= 2) gam = gamma[col];
#pragma unroll
        for (int i = 0; i < 4; ++i) {
#pragma unroll
            for (int r = 0; r < 4; ++r) {
                int row = m0 + wm + i * 16 + quad4 + r;
                float v = acc[i][j][r];
                if (EPI == 0) {
                    Obf[(size_t)row * ldo + col] = f2bf(v);
                } else if (EPI == 1) {
                    float t = v * bscale + bshift;
                    t = 0.5f * t * (1.0f + erff(t * 0.70710678118654752f));
                    ((u8*)Obf)[(size_t)row * ldo + swz(row, col)] = f2e4(t);   // feeds GEMM-A: pre-swizzle
                } else if (EPI == 2) {
                    float t = v * bscale + bshift;
                    xf[(size_t)row * N + col] += gam * t;
                } else if (EPI == 3) {
                    xf[(size_t)row * N + col] += gam * v;
                } else if (EPI == 4) {
                    ofb[(size_t)row * N + col] = xf[(size_t)row * N + col] + gam * v;
                } else {
                    xf[(size_t)row * N + col] = xin[(size_t)row * N + col] + gam * v;
                }
            }
        }
    }
}

// ---------------------------------------------------------------- channel attention, stage 1:
// partial Gram + partial norms over a 128-row N-slice; atomicAdd into f32 accumulators.
// grid (18 slices, 128 bh). qkv stays bf16 (EPI=0 output, NOT swizzled).
__global__ __launch_bounds__(256)
void gram_kernel(const u16* __restrict__ qkv, float* __restrict__ Sacc,
                 float* __restrict__ nrm2) {
    const int bh = blockIdx.y;
    const int b = bh >> 3, h = bh & 7;
    const int tid = threadIdx.x;
    __shared__ float qsf[64][48];
    __shared__ float ksf[64][48];

    float acc9[3][3];
#pragma unroll
    for (int i = 0; i < 3; ++i)
#pragma unroll
        for (int j = 0; j < 3; ++j) acc9[i][j] = 0.f;
    float qn2 = 0.f, kn2 = 0.f;

    const int qoff = h * 48;
    const int koff = 384 + h * 48;
    const int d0 = (tid >> 4) * 3;
    const int e0 = (tid & 15) * 3;
    const int nbase = blockIdx.x * 128;

    for (int c = 0; c < 2; ++c) {
        const int n0 = nbase + c * 64;
#pragma unroll
        for (int it = 0; it < 6; ++it) {
            int chunk = tid + it * 256;          // 0..1535: [q 768 | k 768] chunks of 4 bf16
            int mat = chunk >= 768 ? 1 : 0;
            int rem = chunk - mat * 768;
            int nn = rem / 12, u = rem - nn * 12;
            ushort4 raw = *(const ushort4*)(qkv + (size_t)(b * 2304 + n0 + nn) * 1152 +
                                            (mat ? koff : qoff) + u * 4);
            float4 f = make_float4(bf2f(raw.x), bf2f(raw.y), bf2f(raw.z), bf2f(raw.w));
            if (mat) *(float4*)&ksf[nn][u * 4] = f;
            else     *(float4*)&qsf[nn][u * 4] = f;
        }
        __syncthreads();
#pragma unroll 4
        for (int nn = 0; nn < 64; ++nn) {
            float q0 = qsf[nn][d0], q1 = qsf[nn][d0 + 1], q2 = qsf[nn][d0 + 2];
            float k0v = ksf[nn][e0], k1v = ksf[nn][e0 + 1], k2v = ksf[nn][e0 + 2];
            acc9[0][0] += q0 * k0v; acc9[0][1] += q0 * k1v; acc9[0][2] += q0 * k2v;
            acc9[1][0] += q1 * k0v; acc9[1][1] += q1 * k1v; acc9[1][2] += q1 * k2v;
            acc9[2][0] += q2 * k0v; acc9[2][1] += q2 * k1v; acc9[2][2] += q2 * k2v;
        }
        if (tid < 48) {
            for (int nn = 0; nn < 64; ++nn) { float q = qsf[nn][tid]; qn2 += q * q; }
        } else if (tid >= 128 && tid < 176) {
            int e = tid - 128;
            for (int nn = 0; nn < 64; ++nn) { float k = ksf[nn][e]; kn2 += k * k; }
        }
        __syncthreads();
    }

    float* Sb = Sacc + (size_t)bh * 2304;
#pragma unroll
    for (int i = 0; i < 3; ++i)
#pragma unroll
        for (int j = 0; j < 3; ++j)
            atomicAdd(&Sb[(d0 + i) * 48 + e0 + j], acc9[i][j]);
    if (tid < 48) atomicAdd(&nrm2[bh * 96 + tid], qn2);
    else if (tid >= 128 && tid < 176) atomicAdd(&nrm2[bh * 96 + 48 + (tid - 128)], kn2);
}

// ---------------------------------------------------------------- channel attention, stage 2
__global__ __launch_bounds__(256)
void attn_fin_kernel(const float* __restrict__ Sacc, const float* __restrict__ nrm2,
                     const float* __restrict__ temp, float* __restrict__ attnb) {
    const int bh = blockIdx.x;
    const int h = bh & 7;
    const int tid = threadIdx.x;
    __shared__ float S[48][49];
    __shared__ float qns[48], kns[48];

    const float* Sb = Sacc + (size_t)bh * 2304;
    for (int i = tid; i < 2304; i += 256) {
        int d = i / 48, e = i - d * 48;
        S[d][e] = Sb[i];
    }
    if (tid < 48)      qns[tid]      = fmaxf(sqrtf(nrm2[bh * 96 + tid]), 1e-12f);
    else if (tid < 96) kns[tid - 48] = fmaxf(sqrtf(nrm2[bh * 96 + tid]), 1e-12f);
    __syncthreads();

    if (tid < 48) {
        float tf = temp[h] / qns[tid];
        float mx = -1e30f;
        for (int e = 0; e < 48; ++e) {
            float t = S[tid][e] * tf / kns[e];
            S[tid][e] = t;
            mx = fmaxf(mx, t);
        }
        float sum = 0.f;
        for (int e = 0; e < 48; ++e) { float t = __expf(S[tid][e] - mx); S[tid][e] = t; sum += t; }
        float inv = 1.0f / sum;
        float* dst = attnb + ((size_t)bh * 48 + tid) * 48;
        for (int e = 0; e < 48; ++e) dst[e] = S[tid][e] * inv;
    }
}

// ---------------------------------------------------------------- out[b,n,h*48+d] = sum_e attn[b,h,d,e] * v[b,n,h*48+e]
// writes z as fp8, PRE-SWIZZLED (feeds proj GEMM-A)
__global__ __launch_bounds__(256)
void attnout_kernel(const u16* __restrict__ qkv, const float* __restrict__ attnb,
                    u8* __restrict__ z) {
    const int r0 = blockIdx.x * 64;
    const int h  = blockIdx.y;
    const int b  = r0 / 2304;
    const int tid = threadIdx.x;
    __shared__ float A[48][49];
    __shared__ float vsf[64][48];

    const float* asrc = attnb + (size_t)(b * 8 + h) * 2304;
    for (int i = tid; i < 2304; i += 256) {
        int d = i / 48, e = i - d * 48;
        A[d][e] = asrc[i];
    }
    const int voff = 768 + h * 48;
    for (int i = tid; i < 768; i += 256) {
        int nn = i / 12, u = i - nn * 12;
        ushort4 raw = *(const ushort4*)(qkv + (size_t)(r0 + nn) * 1152 + voff + u * 4);
        float4 f = make_float4(bf2f(raw.x), bf2f(raw.y), bf2f(raw.z), bf2f(raw.w));
        *(float4*)&vsf[nn][u * 4] = f;
    }
    __syncthreads();

    const int rr0 = (tid >> 4) * 4;
    const int d0  = (tid & 15) * 3;
    float acc[4][3];
#pragma unroll
    for (int r = 0; r < 4; ++r)
#pragma unroll
        for (int j = 0; j < 3; ++j) acc[r][j] = 0.f;

#pragma unroll 4
    for (int e = 0; e < 48; ++e) {
        float a0 = A[d0][e], a1 = A[d0 + 1][e], a2 = A[d0 + 2][e];
#pragma unroll
        for (int r = 0; r < 4; ++r) {
            float vv = vsf[rr0 + r][e];
            acc[r][0] += a0 * vv; acc[r][1] += a1 * vv; acc[r][2] += a2 * vv;
        }
    }
#pragma unroll
    for (int r = 0; r < 4; ++r)
#pragma unroll
        for (int j = 0; j < 3; ++j) {
            int row = r0 + rr0 + r;
            int col = h * 48 + d0 + j;
            z[(size_t)row * 384 + swz(row, col)] = f2e4(acc[r][j]);
        }
}

// ---------------------------------------------------------------- conv weight: f32 [O,C,3,3] -> fp8 [O, (dy*3+dx)*384 + c], pre-swizzled
__global__ void reorder_w_kernel(const float* __restrict__ w, u8* __restrict__ wr, int n) {
    int i = blockIdx.x * blockDim.x + threadIdx.x;
    if (i < n) {
        int o = i / 3456, rem = i - o * 3456;
        int j = rem / 384, c = rem - j * 384;
        wr[(size_t)o * 3456 + swz(o, rem)] = f2e4(w[(size_t)(o * 384 + c) * 9 + j]);
    }
}

// ---------------------------------------------------------------- (H, W) tail
__global__ void tail_kernel(const int* __restrict__ Hp, const int* __restrict__ Wp,
                            float* __restrict__ out, size_t base, int n_extra) {
    if (threadIdx.x == 0) {
        if (n_extra >= 1) out[base]     = (float)Hp[0];
        if (n_extra >= 2) out[base + 1] = (float)Wp[0];
    }
}

extern "C" void kernel_launch(void* const* d_in, const int* in_sizes, int n_in,
                              void* d_out, int out_size, void* d_ws, size_t ws_size,
                              hipStream_t stream) {
    const float* x      = (const float*)d_in[0];
    const float* ln1_g  = (const float*)d_in[1];
    const float* ln1_b  = (const float*)d_in[2];
    const float* w_qkv  = (const float*)d_in[3];
    const float* temp   = (const float*)d_in[4];
    const float* w_proj = (const float*)d_in[5];
    const float* gamma1 = (const float*)d_in[6];
    const float* ln2_g  = (const float*)d_in[7];
    const float* ln2_b  = (const float*)d_in[8];
    const float* mlp_w1 = (const float*)d_in[9];
    const float* bn1_g  = (const float*)d_in[10];
    const float* bn1_b  = (const float*)d_in[11];
    const float* bn1_m  = (const float*)d_in[12];
    const float* bn1_v  = (const float*)d_in[13];
    const float* mlp_w2 = (const float*)d_in[14];
    const float* bn2_g  = (const float*)d_in[15];
    const float* bn2_b  = (const float*)d_in[16];
    const float* bn2_m  = (const float*)d_in[17];
    const float* bn2_v  = (const float*)d_in[18];
    const float* gamma2 = (const float*)d_in[19];
    const float* ln3_g  = (const float*)d_in[20];
    const float* ln3_b  = (const float*)d_in[21];
    const float* pconv1 = (const float*)d_in[22];
    const float* pbn_g  = (const float*)d_in[23];
    const float* pbn_b  = (const float*)d_in[24];
    const float* pbn_m  = (const float*)d_in[25];
    const float* pbn_v  = (const float*)d_in[26];
    const float* pconv2 = (const float*)d_in[27];
    const float* gamma3 = (const float*)d_in[28];
    const int* Hp = (const int*)d_in[29];
    const int* Wp = (const int*)d_in[30];

    const int M = 36864, C = 384, C2 = 768, NQKV = 1152, KC = 3456;
    const size_t NBNC = (size_t)M * C;                 // 14,155,776

    const size_t SZ_XF  = NBNC * 4;                    //  f32 residual stream
    const size_t SZ_LN  = NBNC * 2;                    //  fp8 LN out / z (half used)
    const size_t SZ_BIG = (size_t)M * NQKV * 2;        //  bf16 qkv / fp8 mlp hidden / zero page
    const size_t SZ_P3  = SZ_LN;                       //  attnb + weights + Gram accum, later conv1 out
    const size_t SZ_W   = (size_t)C * KC * 2;
    if (ws_size < SZ_XF + SZ_LN + SZ_BIG + SZ_P3 + 2 * SZ_W) return;

    char* ws = (char*)d_ws;
    float* xf     = (float*)ws;
    u8*    lnbuf  = (u8*)(ws + SZ_XF);
    u16*   big    = (u16*)(ws + SZ_XF + SZ_LN);
    char*  p3     = ws + SZ_XF + SZ_LN + SZ_BIG;
    float* attnb  = (float*)p3;                                      // 1,179,648 B
    u8*    wqkvb  = (u8*)(p3 + 1179648);
    u8*    wprojb = (u8*)(p3 + 1179648 + 884736);
    u8*    w1b    = (u8*)(p3 + 1179648 + 884736 + 294912);
    u8*    w2b    = (u8*)(p3 + 1179648 + 884736 + 294912 + 589824);
    float* Sacc   = (float*)(p3 + 3538944);                          // 128*2304 f32
    float* nrm2   = (float*)(p3 + 3538944 + 1179648);                // 128*96 f32
    u8*    convbf = (u8*)p3;                                         // conv1 output (fp8, M*C), block 3 only
    u8*    w1r    = (u8*)(p3 + SZ_P3);
    u8*    w2r    = (u8*)(p3 + SZ_P3 + SZ_W);
    u8*    zp     = (u8*)big;                                        // 4 KB zero page (big dead in block 3)

    const int n_extra = out_size - (int)NBNC;

    // weight conversions (f32 -> fp8 e4m3, pre-swizzled) + Gram accumulator zeroing
    cvt_f2e4_kernel<<<(NQKV * C / 4 + 255) / 256, 256, 0, stream>>>(w_qkv, wqkvb, NQKV * C / 4, C);
    cvt_f2e4_kernel<<<(C * C / 4 + 255) / 256, 256, 0, stream>>>(w_proj, wprojb, C * C / 4, C);
    cvt_f2e4_kernel<<<(C2 * C / 4 + 255) / 256, 256, 0, stream>>>(mlp_w1, w1b, C2 * C / 4, C);
    cvt_f2e4_kernel<<<(C * C2 / 4 + 255) / 256, 256, 0, stream>>>(mlp_w2, w2b, C * C2 / 4, C2);
    zero_f32_kernel<<<(128 * 2304 + 128 * 96 + 255) / 256, 256, 0, stream>>>(
        Sacc, 128 * 2304 + 128 * 96);

    // --- attention block ---  (ln1 reads input x directly)
    ln_kernel<<<M, 64, 0, stream>>>(x, ln1_g, ln1_b, lnbuf);
    gemm_nt<0, 0><<<dim3(NQKV / 128, M / 128), 256, 0, stream>>>(
        lnbuf, wqkvb, M, NQKV, C, big, NQKV, nullptr, nullptr, nullptr,
        nullptr, nullptr, nullptr, nullptr, nullptr, nullptr);
    gram_kernel<<<dim3(18, 128), 256, 0, stream>>>(big, Sacc, nrm2);
    attn_fin_kernel<<<128, 256, 0, stream>>>(Sacc, nrm2, temp, attnb);
    attnout_kernel<<<dim3(M / 64, 8), 256, 0, stream>>>(big, attnb, lnbuf);
    gemm_nt<0, 5><<<dim3(C / 128, M / 128), 256, 0, stream>>>(        // xf = x + gamma1 * proj
        lnbuf, wprojb, M, C, C, nullptr, 0, xf, nullptr, x,
        nullptr, nullptr, nullptr, nullptr, gamma1, nullptr);

    // --- ConvMlp block (1x1 convs + eval BN) ---
    ln_kernel<<<M, 64, 0, stream>>>(xf, ln2_g, ln2_b, lnbuf);
    gemm_nt<0, 1><<<dim3(C2 / 128, M / 128), 256, 0, stream>>>(
        lnbuf, w1b, M, C2, C, (u16*)big, C2, nullptr, nullptr, nullptr,
        bn1_g, bn1_b, bn1_m, bn1_v, nullptr, nullptr);
    gemm_nt<0, 2><<<dim3(C / 128, M / 128), 256, 0, stream>>>(
        (u8*)big, w2b, M, C, C2, nullptr, 0, xf, nullptr, nullptr,
        bn2_g, bn2_b, bn2_m, bn2_v, gamma2, nullptr);

    // --- projection block (3x3 conv -> BN -> GELU -> 3x3 conv), implicit im2col GEMMs ---
    ln_kernel<<<M, 64, 0, stream>>>(xf, ln3_g, ln3_b, lnbuf);
    reorder_w_kernel<<<(C * KC + 255) / 256, 256, 0, stream>>>(pconv1, w1r, C * KC);
    reorder_w_kernel<<<(C * KC + 255) / 256, 256, 0, stream>>>(pconv2, w2r, C * KC);
    zero_kernel<<<8, 256, 0, stream>>>((u16*)zp, 2048);    // 4 KB zero page for im2col halo
    gemm_nt<1, 1><<<dim3(C / 128, M / 128), 256, 0, stream>>>(
        lnbuf, w1r, M, C, KC, (u16*)convbf, C, nullptr, nullptr, nullptr,
        pbn_g, pbn_b, pbn_m, pbn_v, nullptr, zp);
    gemm_nt<1, 4><<<dim3(C / 128, M / 128), 256, 0, stream>>>(
        convbf, w2r, M, C, KC, nullptr, 0, xf, (float*)d_out, nullptr,
        nullptr, nullptr, nullptr, nullptr, gamma3, zp);

    tail_kernel<<<1, 64, 0, stream>>>(Hp, Wp, (float*)d_out, NBNC, n_extra);
}

// Round 8
// 675.058 us; speedup vs baseline: 1.1022x; 1.1022x over previous
//
#include <hip/hip_runtime.h>
#include <hip/hip_bf16.h>

typedef unsigned short u16;
typedef unsigned char  u8;
typedef __attribute__((ext_vector_type(4))) float floatx4;  // MFMA C/D frag

#define LN_EPS 1e-5f

__device__ __forceinline__ float bf2f(u16 u) {
    unsigned int i = ((unsigned int)u) << 16;
    float f; __builtin_memcpy(&f, &i, 4); return f;
}
__device__ __forceinline__ u16 f2bf(float f) {
    __hip_bfloat16 h = __float2bfloat16(f);   // RNE
    u16 u; __builtin_memcpy(&u, &h, 2); return u;
}
// f32 -> OCP e4m3fn via HW packed convert (self-consistent with fp8 MFMA)
__device__ __forceinline__ u8 f2e4(float f) {
    int p = __builtin_amdgcn_cvt_pk_fp8_f32(f, f, 0, false);
    return (u8)(p & 0xff);
}

// GEMM-operand global pre-swizzle (ACONV=0 operands + conv B): row m stores k-byte at
//   phys(m, k) = (k & ~63) | (((k>>3) + (m>>1)) & 7)*8 | (k & 7)
// -> LDS staging is a verbatim linear row copy; ds_read_b64 at slot (s + (row>>1))&7
//    puts a 16-lane quarter-group on all 32 banks exactly once (zero conflicts, r7-verified).
__device__ __forceinline__ int swz(int m, int k) {
    return (k & ~63) | (((((k >> 3) + (m >> 1)) & 7) << 3)) | (k & 7);
}

// async global->LDS, 16 B per lane; lds dest must be wave-uniform (HW adds lane*16)
__device__ __forceinline__ void gl_lds16(const u8* g, u8* l) {
    __builtin_amdgcn_global_load_lds(
        (const __attribute__((address_space(1))) void*)(const void*)g,
        (__attribute__((address_space(3))) void*)(void*)l,
        16, 0, 0);
}

// ---------------------------------------------------------------- f32 -> fp8 e4m3 (weights, pre-swizzled rows)
__global__ void cvt_f2e4_kernel(const float* __restrict__ in, u8* __restrict__ out,
                                int n4, int Kp) {
    int i = blockIdx.x * blockDim.x + threadIdx.x;
    if (i < n4) {
        float4 f = ((const float4*)in)[i];
        uchar4 o; o.x = f2e4(f.x); o.y = f2e4(f.y); o.z = f2e4(f.z); o.w = f2e4(f.w);
        int e = i * 4;
        int n = e / Kp, k = e - n * Kp;          // 4 bytes stay inside one 8-B slot (k&7 in {0,4})
        *(uchar4*)(out + (size_t)n * Kp + swz(n, k)) = o;
    }
}

__global__ void zero_kernel(u16* __restrict__ p, int n) {
    int i = blockIdx.x * blockDim.x + threadIdx.x;
    if (i < n) p[i] = 0;
}

__global__ void zero_f32_kernel(float* __restrict__ p, int n) {
    int i = blockIdx.x * blockDim.x + threadIdx.x;
    if (i < n) p[i] = 0.f;
}

// ---------------------------------------------------------------- LayerNorm over C=384 -> fp8
// SWZ=1: pre-swizzled rows (feeds ACONV=0 GEMM A).  SWZ=0: linear rows (feeds conv1 im2col A).
template<bool SWZ>
__global__ __launch_bounds__(64)
void ln_kernel(const float* __restrict__ xf, const float* __restrict__ g,
               const float* __restrict__ b, u8* __restrict__ out) {
    const int row = blockIdx.x;
    const int lane = threadIdx.x;
    const float* xr = xf + (size_t)row * 384;
    float v[6], s = 0.f, s2 = 0.f;
#pragma unroll
    for (int i = 0; i < 6; ++i) { v[i] = xr[lane + i * 64]; s += v[i]; s2 += v[i] * v[i]; }
#pragma unroll
    for (int off = 32; off; off >>= 1) { s += __shfl_xor(s, off); s2 += __shfl_xor(s2, off); }
    float mean = s * (1.0f / 384.0f);
    float var  = s2 * (1.0f / 384.0f) - mean * mean;
    float rstd = rsqrtf(var + LN_EPS);
    u8* orow = out + (size_t)row * 384;
    int pofs = lane;
    if (SWZ) {
        const int gperm = (row >> 1) & 7;
        pofs = ((((lane >> 3) + gperm) & 7) << 3) | (lane & 7);
    }
#pragma unroll
    for (int i = 0; i < 6; ++i) {
        int c = lane + i * 64;
        orow[i * 64 + pofs] = f2e4((v[i] - mean) * rstd * g[c] + b[c]);
    }
}

// ---------------------------------------------------------------- MFMA NT GEMM (fp8 e4m3 A,B): C = A[M,K] * B[N,K]^T
// 128x128 tile, BK=64, 256 thr / 4 waves (64x64/wave), dbuf LDS 32 KB -> 4 blk/CU.
// B operand + plain-A: GLOBALLY pre-swizzled (swz) -> linear staging + 8-slot read = ZERO
// bank conflicts (r7-verified). Conv A (im2col, rows shift per tap): r6's LDS-LOCAL 4-chunk
// rotation -- keyed by LDS row, tap-invariant, NO in-loop read recompute (r7's per-tap
// read-side machinery caused a 13% stall regression); residual 2-way b64 conflict on A only.
// Sync = r2's proven minimal loop: {mfma; lgkm0; bar; STAGE(t+2); counted vmcnt(4); bar}.
// ACONV: 0 plain A[M,K] (pre-swizzled); 1 implicit im2col (H=W=48, K=3456, linear source).
// EPI: 0 bf16 store; 1 BN+GELU->fp8 (SWZO: pre-swizzled vs linear); 2 BN -> xf += gamma*v;
//      3 xf += gamma*v; 4 ofb = xf + gamma*v; 5 xf = xin + gamma*v
template<int ACONV, int EPI, bool SWZO = false>
__global__ __launch_bounds__(256, 4)
void gemm_nt(const u8* __restrict__ A, const u8* __restrict__ Bm,
             int M, int N, int K,
             u16* __restrict__ Obf, int ldo,
             float* __restrict__ xf, float* __restrict__ ofb, const float* __restrict__ xin,
             const float* __restrict__ bn_g, const float* __restrict__ bn_b,
             const float* __restrict__ bn_m, const float* __restrict__ bn_v,
             const float* __restrict__ gamma, const u8* __restrict__ zp) {
    __shared__ u8 As[2][128 * 64];
    __shared__ u8 Bs[2][128 * 64];

    const int tid = threadIdx.x;
    // XCD swizzle: L = (g%8)*(G/8) + g/8 ; n_tile = L % gx (fast), m_tile = L / gx
    const int gx = gridDim.x;
    const int g  = blockIdx.y * gx + blockIdx.x;
    const int G  = gx * gridDim.y;
    int L = g;
    if ((G & 7) == 0) L = (g & 7) * (G >> 3) + (g >> 3);
    const int n0 = (L % gx) * 128;
    const int m0 = (L / gx) * 128;

    const int lane  = tid & 63;
    const int wave  = tid >> 6;
    const int wm    = (wave >> 1) * 64;
    const int wn    = (wave & 1) * 64;
    const int fr    = lane & 15;
    const int klane = lane >> 4;

    int arow[4], brow[4];
#pragma unroll
    for (int i = 0; i < 4; ++i) {
        arow[i] = (wm + i * 16 + fr) * 64;
        brow[i] = (wn + i * 16 + fr) * 64;
    }
    // 8-slot pre-swizzle read (B always; A when ACONV=0): slot = (kh*4 + klane + fr>>1) & 7
    int csw8[2];
#pragma unroll
    for (int kh = 0; kh < 2; ++kh)
        csw8[kh] = ((((kh << 2) + klane) + (fr >> 1)) & 7) << 3;
    // 4-chunk LDS-local rotation read (conv A): chunk = (kh*2 + klane>>1 + fr>>1) & 3
    int csw4[2];
#pragma unroll
    for (int kh = 0; kh < 2; ++kh)
        csw4[kh] = ((((kh << 1) + (klane >> 1) + (fr >> 1)) & 3) << 4) + ((klane & 1) << 3);

    // staging: thread stages 16 B at LDS row (q*64 + tid>>2), phys chunk (tid&3)
    const int srow = tid >> 2;
    const int scol = (tid & 3) << 4;                                  // linear (pre-swizzled src)
    const int ssc4 = ((((tid & 3) - ((tid >> 3) & 3)) & 3) << 4);     // rotation src (conv A)
    const u8 *sa[2], *sb[2];
    const u8* imgq[2];
    int ay[2], ax[2];
#pragma unroll
    for (int q = 0; q < 2; ++q) {
        int r = q * 64 + srow;
        if (ACONV == 0) {
            sa[q] = A + (size_t)(m0 + r) * K + scol;
        } else {
            int nA = m0 + r;
            int bi = nA / 2304;                  // 128-tile never crosses image (128 | 2304)
            int nl = nA - bi * 2304;
            ay[q] = nl / 48;
            ax[q] = nl - ay[q] * 48;
            imgq[q] = A + (size_t)bi * 2304 * 384;
        }
        sb[q] = Bm + (size_t)(n0 + q * 64 + srow) * K + scol;
    }

    int scnt = 0, sjj = 0;
    const int NT = K / 64;

    auto STAGE = [&](int d) {
        if (ACONV == 1) {
            if (scnt == 0) {                     // new 3x3 tap: recompute A pointers
                int t3 = sjj / 3;
                int dy = t3 - 1, dx = sjj - t3 * 3 - 1;
                ++sjj;
#pragma unroll
                for (int q = 0; q < 2; ++q) {
                    int yy = ay[q] + dy, xx = ax[q] + dx;
                    bool v = ((unsigned)yy < 48u) & ((unsigned)xx < 48u);
                    sa[q] = (v ? imgq[q] + (size_t)(yy * 48 + xx) * 384 : zp) + ssc4;
                }
            }
            scnt = (scnt == 5) ? 0 : scnt + 1;
        }
        u8* la = &As[d][0];
        u8* lb = &Bs[d][0];
        gl_lds16(sa[0], la + ((wave * 64) << 4));        sa[0] += 64;
        gl_lds16(sa[1], la + ((256 + wave * 64) << 4));  sa[1] += 64;
        gl_lds16(sb[0], lb + ((wave * 64) << 4));        sb[0] += 64;
        gl_lds16(sb[1], lb + ((256 + wave * 64) << 4));  sb[1] += 64;
    };

    floatx4 acc[4][4];
#pragma unroll
    for (int i = 0; i < 4; ++i)
#pragma unroll
        for (int j = 0; j < 4; ++j) acc[i][j] = (floatx4){0.f, 0.f, 0.f, 0.f};

    // prologue: tiles 0,1 in flight (4 loads each per thread); counted wait on tile 0 only
    STAGE(0);
    STAGE(1);
    asm volatile("s_waitcnt vmcnt(4)" ::: "memory");
    __builtin_amdgcn_s_barrier();
    asm volatile("" ::: "memory");

    int cur = 0;
    for (int t = 0; t < NT; ++t) {
        const u8* Ab = &As[cur][0];
        const u8* Bb = &Bs[cur][0];
#pragma unroll
        for (int kh = 0; kh < 2; ++kh) {
            long af[4], bfr[4];
#pragma unroll
            for (int i = 0; i < 4; ++i) af[i]  = *(const long*)(Ab + arow[i] + (ACONV ? csw4[kh] : csw8[kh]));
#pragma unroll
            for (int j = 0; j < 4; ++j)  bfr[j] = *(const long*)(Bb + brow[j] + csw8[kh]);
#pragma unroll
            for (int i = 0; i < 4; ++i)
#pragma unroll
                for (int j = 0; j < 4; ++j)
                    acc[i][j] = __builtin_amdgcn_mfma_f32_16x16x32_fp8_fp8(af[i], bfr[j], acc[i][j], 0, 0, 0);
        }
        asm volatile("s_waitcnt lgkmcnt(0)" ::: "memory");   // this wave's reads of buf[cur] done
        __builtin_amdgcn_s_barrier();                        // all waves done -> buf[cur] free
        asm volatile("" ::: "memory");
        if (t + 2 < NT) {
            STAGE(cur);                                      // issue tile t+2 into freed buffer
            asm volatile("s_waitcnt vmcnt(4)" ::: "memory"); // drain tile t+1 (issued 1 tile ago)
        } else {
            asm volatile("s_waitcnt vmcnt(0)" ::: "memory"); // tail: nothing new issued
        }
        __builtin_amdgcn_sched_barrier(0);
        __builtin_amdgcn_s_barrier();                        // tile t+1 resident for all waves
        asm volatile("" ::: "memory");
        cur ^= 1;
    }

    // Epilogue. C/D layout: col = lane&15, row = (lane>>4)*4 + reg  [dtype-independent, m121-128]
    const int quad4 = (lane >> 4) * 4;
#pragma unroll
    for (int j = 0; j < 4; ++j) {
        int col = n0 + wn + j * 16 + fr;
        float bscale = 0.f, bshift = 0.f, gam = 0.f;
        if (EPI == 1 || EPI == 2) {
            bscale = bn_g[col] * rsqrtf(bn_v[col] + LN_EPS);
            bshift = bn_b[col] - bn_m[col] * bscale;
        }
        if (EPI >= 2) gam = gamma[col];
#pragma unroll
        for (int i = 0; i < 4; ++i) {
#pragma unroll
            for (int r = 0; r < 4; ++r) {
                int row = m0 + wm + i * 16 + quad4 + r;
                float v = acc[i][j][r];
                if (EPI == 0) {
                    Obf[(size_t)row * ldo + col] = f2bf(v);
                } else if (EPI == 1) {
                    float t = v * bscale + bshift;
                    t = 0.5f * t * (1.0f + erff(t * 0.70710678118654752f));
                    int oc = SWZO ? swz(row, col) : col;
                    ((u8*)Obf)[(size_t)row * ldo + oc] = f2e4(t);
                } else if (EPI == 2) {
                    float t = v * bscale + bshift;
                    xf[(size_t)row * N + col] += gam * t;
                } else if (EPI == 3) {
                    xf[(size_t)row * N + col] += gam * v;
                } else if (EPI == 4) {
                    ofb[(size_t)row * N + col] = xf[(size_t)row * N + col] + gam * v;
                } else {
                    xf[(size_t)row * N + col] = xin[(size_t)row * N + col] + gam * v;
                }
            }
        }
    }
}

// ---------------------------------------------------------------- channel attention, stage 1:
// partial Gram + partial norms over a 128-row N-slice; atomicAdd into f32 accumulators.
// grid (18 slices, 128 bh). qkv stays bf16 (EPI=0 output, NOT swizzled).
__global__ __launch_bounds__(256)
void gram_kernel(const u16* __restrict__ qkv, float* __restrict__ Sacc,
                 float* __restrict__ nrm2) {
    const int bh = blockIdx.y;
    const int b = bh >> 3, h = bh & 7;
    const int tid = threadIdx.x;
    __shared__ float qsf[64][48];
    __shared__ float ksf[64][48];

    float acc9[3][3];
#pragma unroll
    for (int i = 0; i < 3; ++i)
#pragma unroll
        for (int j = 0; j < 3; ++j) acc9[i][j] = 0.f;
    float qn2 = 0.f, kn2 = 0.f;

    const int qoff = h * 48;
    const int koff = 384 + h * 48;
    const int d0 = (tid >> 4) * 3;
    const int e0 = (tid & 15) * 3;
    const int nbase = blockIdx.x * 128;

    for (int c = 0; c < 2; ++c) {
        const int n0 = nbase + c * 64;
#pragma unroll
        for (int it = 0; it < 6; ++it) {
            int chunk = tid + it * 256;          // 0..1535: [q 768 | k 768] chunks of 4 bf16
            int mat = chunk >= 768 ? 1 : 0;
            int rem = chunk - mat * 768;
            int nn = rem / 12, u = rem - nn * 12;
            ushort4 raw = *(const ushort4*)(qkv + (size_t)(b * 2304 + n0 + nn) * 1152 +
                                            (mat ? koff : qoff) + u * 4);
            float4 f = make_float4(bf2f(raw.x), bf2f(raw.y), bf2f(raw.z), bf2f(raw.w));
            if (mat) *(float4*)&ksf[nn][u * 4] = f;
            else     *(float4*)&qsf[nn][u * 4] = f;
        }
        __syncthreads();
#pragma unroll 4
        for (int nn = 0; nn < 64; ++nn) {
            float q0 = qsf[nn][d0], q1 = qsf[nn][d0 + 1], q2 = qsf[nn][d0 + 2];
            float k0v = ksf[nn][e0], k1v = ksf[nn][e0 + 1], k2v = ksf[nn][e0 + 2];
            acc9[0][0] += q0 * k0v; acc9[0][1] += q0 * k1v; acc9[0][2] += q0 * k2v;
            acc9[1][0] += q1 * k0v; acc9[1][1] += q1 * k1v; acc9[1][2] += q1 * k2v;
            acc9[2][0] += q2 * k0v; acc9[2][1] += q2 * k1v; acc9[2][2] += q2 * k2v;
        }
        if (tid < 48) {
            for (int nn = 0; nn < 64; ++nn) { float q = qsf[nn][tid]; qn2 += q * q; }
        } else if (tid >= 128 && tid < 176) {
            int e = tid - 128;
            for (int nn = 0; nn < 64; ++nn) { float k = ksf[nn][e]; kn2 += k * k; }
        }
        __syncthreads();
    }

    float* Sb = Sacc + (size_t)bh * 2304;
#pragma unroll
    for (int i = 0; i < 3; ++i)
#pragma unroll
        for (int j = 0; j < 3; ++j)
            atomicAdd(&Sb[(d0 + i) * 48 + e0 + j], acc9[i][j]);
    if (tid < 48) atomicAdd(&nrm2[bh * 96 + tid], qn2);
    else if (tid >= 128 && tid < 176) atomicAdd(&nrm2[bh * 96 + 48 + (tid - 128)], kn2);
}

// ---------------------------------------------------------------- channel attention, stage 2
__global__ __launch_bounds__(256)
void attn_fin_kernel(const float* __restrict__ Sacc, const float* __restrict__ nrm2,
                     const float* __restrict__ temp, float* __restrict__ attnb) {
    const int bh = blockIdx.x;
    const int h = bh & 7;
    const int tid = threadIdx.x;
    __shared__ float S[48][49];
    __shared__ float qns[48], kns[48];

    const float* Sb = Sacc + (size_t)bh * 2304;
    for (int i = tid; i < 2304; i += 256) {
        int d = i / 48, e = i - d * 48;
        S[d][e] = Sb[i];
    }
    if (tid < 48)      qns[tid]      = fmaxf(sqrtf(nrm2[bh * 96 + tid]), 1e-12f);
    else if (tid < 96) kns[tid - 48] = fmaxf(sqrtf(nrm2[bh * 96 + tid]), 1e-12f);
    __syncthreads();

    if (tid < 48) {
        float tf = temp[h] / qns[tid];
        float mx = -1e30f;
        for (int e = 0; e < 48; ++e) {
            float t = S[tid][e] * tf / kns[e];
            S[tid][e] = t;
            mx = fmaxf(mx, t);
        }
        float sum = 0.f;
        for (int e = 0; e < 48; ++e) { float t = __expf(S[tid][e] - mx); S[tid][e] = t; sum += t; }
        float inv = 1.0f / sum;
        float* dst = attnb + ((size_t)bh * 48 + tid) * 48;
        for (int e = 0; e < 48; ++e) dst[e] = S[tid][e] * inv;
    }
}

// ---------------------------------------------------------------- out[b,n,h*48+d] = sum_e attn[b,h,d,e] * v[b,n,h*48+e]
// writes z as fp8, PRE-SWIZZLED (feeds proj GEMM-A, ACONV=0)
__global__ __launch_bounds__(256)
void attnout_kernel(const u16* __restrict__ qkv, const float* __restrict__ attnb,
                    u8* __restrict__ z) {
    const int r0 = blockIdx.x * 64;
    const int h  = blockIdx.y;
    const int b  = r0 / 2304;
    const int tid = threadIdx.x;
    __shared__ float A[48][49];
    __shared__ float vsf[64][48];

    const float* asrc = attnb + (size_t)(b * 8 + h) * 2304;
    for (int i = tid; i < 2304; i += 256) {
        int d = i / 48, e = i - d * 48;
        A[d][e] = asrc[i];
    }
    const int voff = 768 + h * 48;
    for (int i = tid; i < 768; i += 256) {
        int nn = i / 12, u = i - nn * 12;
        ushort4 raw = *(const ushort4*)(qkv + (size_t)(r0 + nn) * 1152 + voff + u * 4);
        float4 f = make_float4(bf2f(raw.x), bf2f(raw.y), bf2f(raw.z), bf2f(raw.w));
        *(float4*)&vsf[nn][u * 4] = f;
    }
    __syncthreads();

    const int rr0 = (tid >> 4) * 4;
    const int d0  = (tid & 15) * 3;
    float acc[4][3];
#pragma unroll
    for (int r = 0; r < 4; ++r)
#pragma unroll
        for (int j = 0; j < 3; ++j) acc[r][j] = 0.f;

#pragma unroll 4
    for (int e = 0; e < 48; ++e) {
        float a0 = A[d0][e], a1 = A[d0 + 1][e], a2 = A[d0 + 2][e];
#pragma unroll
        for (int r = 0; r < 4; ++r) {
            float vv = vsf[rr0 + r][e];
            acc[r][0] += a0 * vv; acc[r][1] += a1 * vv; acc[r][2] += a2 * vv;
        }
    }
#pragma unroll
    for (int r = 0; r < 4; ++r)
#pragma unroll
        for (int j = 0; j < 3; ++j) {
            int row = r0 + rr0 + r;
            int col = h * 48 + d0 + j;
            z[(size_t)row * 384 + swz(row, col)] = f2e4(acc[r][j]);
        }
}

// ---------------------------------------------------------------- conv weight: f32 [O,C,3,3] -> fp8 [O, (dy*3+dx)*384 + c], pre-swizzled
// (conv B rows never shift -> swz is safe and conflict-free on the B read path)
__global__ void reorder_w_kernel(const float* __restrict__ w, u8* __restrict__ wr, int n) {
    int i = blockIdx.x * blockDim.x + threadIdx.x;
    if (i < n) {
        int o = i / 3456, rem = i - o * 3456;
        int j = rem / 384, c = rem - j * 384;
        wr[(size_t)o * 3456 + swz(o, rem)] = f2e4(w[(size_t)(o * 384 + c) * 9 + j]);
    }
}

// ---------------------------------------------------------------- (H, W) tail
__global__ void tail_kernel(const int* __restrict__ Hp, const int* __restrict__ Wp,
                            float* __restrict__ out, size_t base, int n_extra) {
    if (threadIdx.x == 0) {
        if (n_extra >= 1) out[base]     = (float)Hp[0];
        if (n_extra >= 2) out[base + 1] = (float)Wp[0];
    }
}

extern "C" void kernel_launch(void* const* d_in, const int* in_sizes, int n_in,
                              void* d_out, int out_size, void* d_ws, size_t ws_size,
                              hipStream_t stream) {
    const float* x      = (const float*)d_in[0];
    const float* ln1_g  = (const float*)d_in[1];
    const float* ln1_b  = (const float*)d_in[2];
    const float* w_qkv  = (const float*)d_in[3];
    const float* temp   = (const float*)d_in[4];
    const float* w_proj = (const float*)d_in[5];
    const float* gamma1 = (const float*)d_in[6];
    const float* ln2_g  = (const float*)d_in[7];
    const float* ln2_b  = (const float*)d_in[8];
    const float* mlp_w1 = (const float*)d_in[9];
    const float* bn1_g  = (const float*)d_in[10];
    const float* bn1_b  = (const float*)d_in[11];
    const float* bn1_m  = (const float*)d_in[12];
    const float* bn1_v  = (const float*)d_in[13];
    const float* mlp_w2 = (const float*)d_in[14];
    const float* bn2_g  = (const float*)d_in[15];
    const float* bn2_b  = (const float*)d_in[16];
    const float* bn2_m  = (const float*)d_in[17];
    const float* bn2_v  = (const float*)d_in[18];
    const float* gamma2 = (const float*)d_in[19];
    const float* ln3_g  = (const float*)d_in[20];
    const float* ln3_b  = (const float*)d_in[21];
    const float* pconv1 = (const float*)d_in[22];
    const float* pbn_g  = (const float*)d_in[23];
    const float* pbn_b  = (const float*)d_in[24];
    const float* pbn_m  = (const float*)d_in[25];
    const float* pbn_v  = (const float*)d_in[26];
    const float* pconv2 = (const float*)d_in[27];
    const float* gamma3 = (const float*)d_in[28];
    const int* Hp = (const int*)d_in[29];
    const int* Wp = (const int*)d_in[30];

    const int M = 36864, C = 384, C2 = 768, NQKV = 1152, KC = 3456;
    const size_t NBNC = (size_t)M * C;                 // 14,155,776

    const size_t SZ_XF  = NBNC * 4;                    //  f32 residual stream
    const size_t SZ_LN  = NBNC * 2;                    //  fp8 LN out / z (half used)
    const size_t SZ_BIG = (size_t)M * NQKV * 2;        //  bf16 qkv / fp8 mlp hidden / zero page
    const size_t SZ_P3  = SZ_LN;                       //  attnb + weights + Gram accum, later conv1 out
    const size_t SZ_W   = (size_t)C * KC * 2;
    if (ws_size < SZ_XF + SZ_LN + SZ_BIG + SZ_P3 + 2 * SZ_W) return;

    char* ws = (char*)d_ws;
    float* xf     = (float*)ws;
    u8*    lnbuf  = (u8*)(ws + SZ_XF);
    u16*   big    = (u16*)(ws + SZ_XF + SZ_LN);
    char*  p3     = ws + SZ_XF + SZ_LN + SZ_BIG;
    float* attnb  = (float*)p3;                                      // 1,179,648 B
    u8*    wqkvb  = (u8*)(p3 + 1179648);
    u8*    wprojb = (u8*)(p3 + 1179648 + 884736);
    u8*    w1b    = (u8*)(p3 + 1179648 + 884736 + 294912);
    u8*    w2b    = (u8*)(p3 + 1179648 + 884736 + 294912 + 589824);
    float* Sacc   = (float*)(p3 + 3538944);                          // 128*2304 f32
    float* nrm2   = (float*)(p3 + 3538944 + 1179648);                // 128*96 f32
    u8*    convbf = (u8*)p3;                                         // conv1 output (fp8, M*C), block 3 only
    u8*    w1r    = (u8*)(p3 + SZ_P3);
    u8*    w2r    = (u8*)(p3 + SZ_P3 + SZ_W);
    u8*    zp     = (u8*)big;                                        // 4 KB zero page (big dead in block 3)

    const int n_extra = out_size - (int)NBNC;

    // weight conversions (f32 -> fp8 e4m3, pre-swizzled) + Gram accumulator zeroing
    cvt_f2e4_kernel<<<(NQKV * C / 4 + 255) / 256, 256, 0, stream>>>(w_qkv, wqkvb, NQKV * C / 4, C);
    cvt_f2e4_kernel<<<(C * C / 4 + 255) / 256, 256, 0, stream>>>(w_proj, wprojb, C * C / 4, C);
    cvt_f2e4_kernel<<<(C2 * C / 4 + 255) / 256, 256, 0, stream>>>(mlp_w1, w1b, C2 * C / 4, C);
    cvt_f2e4_kernel<<<(C * C2 / 4 + 255) / 256, 256, 0, stream>>>(mlp_w2, w2b, C * C2 / 4, C2);
    zero_f32_kernel<<<(128 * 2304 + 128 * 96 + 255) / 256, 256, 0, stream>>>(
        Sacc, 128 * 2304 + 128 * 96);

    // --- attention block ---  (ln1 reads input x directly)
    ln_kernel<true><<<M, 64, 0, stream>>>(x, ln1_g, ln1_b, lnbuf);
    gemm_nt<0, 0><<<dim3(NQKV / 128, M / 128), 256, 0, stream>>>(
        lnbuf, wqkvb, M, NQKV, C, big, NQKV, nullptr, nullptr, nullptr,
        nullptr, nullptr, nullptr, nullptr, nullptr, nullptr);
    gram_kernel<<<dim3(18, 128), 256, 0, stream>>>(big, Sacc, nrm2);
    attn_fin_kernel<<<128, 256, 0, stream>>>(Sacc, nrm2, temp, attnb);
    attnout_kernel<<<dim3(M / 64, 8), 256, 0, stream>>>(big, attnb, lnbuf);
    gemm_nt<0, 5><<<dim3(C / 128, M / 128), 256, 0, stream>>>(        // xf = x + gamma1 * proj
        lnbuf, wprojb, M, C, C, nullptr, 0, xf, nullptr, x,
        nullptr, nullptr, nullptr, nullptr, gamma1, nullptr);

    // --- ConvMlp block (1x1 convs + eval BN) ---
    ln_kernel<true><<<M, 64, 0, stream>>>(xf, ln2_g, ln2_b, lnbuf);
    gemm_nt<0, 1, true><<<dim3(C2 / 128, M / 128), 256, 0, stream>>>(
        lnbuf, w1b, M, C2, C, (u16*)big, C2, nullptr, nullptr, nullptr,
        bn1_g, bn1_b, bn1_m, bn1_v, nullptr, nullptr);
    gemm_nt<0, 2><<<dim3(C / 128, M / 128), 256, 0, stream>>>(
        (u8*)big, w2b, M, C, C2, nullptr, 0, xf, nullptr, nullptr,
        bn2_g, bn2_b, bn2_m, bn2_v, gamma2, nullptr);

    // --- projection block (3x3 conv -> BN -> GELU -> 3x3 conv), implicit im2col GEMMs ---
    ln_kernel<false><<<M, 64, 0, stream>>>(xf, ln3_g, ln3_b, lnbuf);   // linear (conv A source)
    reorder_w_kernel<<<(C * KC + 255) / 256, 256, 0, stream>>>(pconv1, w1r, C * KC);
    reorder_w_kernel<<<(C * KC + 255) / 256, 256, 0, stream>>>(pconv2, w2r, C * KC);
    zero_kernel<<<8, 256, 0, stream>>>((u16*)zp, 2048);    // 4 KB zero page for im2col halo
    gemm_nt<1, 1, false><<<dim3(C / 128, M / 128), 256, 0, stream>>>(  // convbf linear (conv2 A source)
        lnbuf, w1r, M, C, KC, (u16*)convbf, C, nullptr, nullptr, nullptr,
        pbn_g, pbn_b, pbn_m, pbn_v, nullptr, zp);
    gemm_nt<1, 4><<<dim3(C / 128, M / 128), 256, 0, stream>>>(
        convbf, w2r, M, C, KC, nullptr, 0, xf, (float*)d_out, nullptr,
        nullptr, nullptr, nullptr, nullptr, gamma3, zp);

    tail_kernel<<<1, 64, 0, stream>>>(Hp, Wp, (float*)d_out, NBNC, n_extra);
}

// Round 9
// 654.981 us; speedup vs baseline: 1.1359x; 1.0307x over previous
//
#include <hip/hip_runtime.h>
#include <hip/hip_bf16.h>

typedef unsigned short u16;
typedef unsigned char  u8;
typedef __attribute__((ext_vector_type(4))) float floatx4;  // MFMA C/D frag

#define LN_EPS 1e-5f

__device__ __forceinline__ float bf2f(u16 u) {
    unsigned int i = ((unsigned int)u) << 16;
    float f; __builtin_memcpy(&f, &i, 4); return f;
}
__device__ __forceinline__ u16 f2bf(float f) {
    __hip_bfloat16 h = __float2bfloat16(f);   // RNE
    u16 u; __builtin_memcpy(&u, &h, 2); return u;
}
// f32 -> OCP e4m3fn via HW packed convert (self-consistent with fp8 MFMA)
__device__ __forceinline__ u8 f2e4(float f) {
    int p = __builtin_amdgcn_cvt_pk_fp8_f32(f, f, 0, false);
    return (u8)(p & 0xff);
}

// GEMM-operand global pre-swizzle (ACONV=0 operands + conv B): row m stores k-byte at
//   phys(m, k) = (k & ~63) | (((k>>3) + (m>>1)) & 7)*8 | (k & 7)
// -> LDS staging is a verbatim linear row copy; ds_read_b64 at slot (s + (row>>1))&7
//    puts a 16-lane quarter-group on all 32 banks exactly once (zero conflicts, r7-verified).
__device__ __forceinline__ int swz(int m, int k) {
    return (k & ~63) | (((((k >> 3) + (m >> 1)) & 7) << 3)) | (k & 7);
}

// async global->LDS, 16 B per lane; lds dest must be wave-uniform (HW adds lane*16)
__device__ __forceinline__ void gl_lds16(const u8* g, u8* l) {
    __builtin_amdgcn_global_load_lds(
        (const __attribute__((address_space(1))) void*)(const void*)g,
        (__attribute__((address_space(3))) void*)(void*)l,
        16, 0, 0);
}

// ---------------------------------------------------------------- merged prep: 4x cvt (f32->fp8,
// pre-swizzled), Sacc/nrm2 zero, 2x conv-weight reorder, zero page, H/W tail. One launch.
__device__ __forceinline__ void cvt4_body(const float* __restrict__ in, u8* __restrict__ out,
                                          int i, int Kp) {
    float4 f = ((const float4*)in)[i];
    uchar4 o; o.x = f2e4(f.x); o.y = f2e4(f.y); o.z = f2e4(f.z); o.w = f2e4(f.w);
    int e = i * 4;
    int n = e / Kp, k = e - n * Kp;              // 4 bytes stay inside one 8-B slot
    *(uchar4*)(out + (size_t)n * Kp + swz(n, k)) = o;
}
__device__ __forceinline__ void reord_body(const float* __restrict__ w, u8* __restrict__ wr,
                                           int i) {
    int o = i / 3456, rem = i - o * 3456;
    int j = rem / 384, c = rem - j * 384;
    wr[(size_t)o * 3456 + swz(o, rem)] = f2e4(w[(size_t)(o * 384 + c) * 9 + j]);
}

__global__ __launch_bounds__(256)
void prep_kernel(const float* __restrict__ w_qkv, u8* __restrict__ wqkvb,
                 const float* __restrict__ w_proj, u8* __restrict__ wprojb,
                 const float* __restrict__ mlp_w1, u8* __restrict__ w1b,
                 const float* __restrict__ mlp_w2, u8* __restrict__ w2b,
                 float* __restrict__ Sacc,                     // zero 307200 f32 (Sacc+nrm2)
                 const float* __restrict__ pconv1, u8* __restrict__ w1r,
                 const float* __restrict__ pconv2, u8* __restrict__ w2r,
                 unsigned int* __restrict__ zp,                // zero 1024 u32 (4 KB page)
                 const int* __restrict__ Hp, const int* __restrict__ Wp,
                 float* __restrict__ dout, size_t base, int n_extra) {
    int i = blockIdx.x * 256 + threadIdx.x;
    if (i < 110592)                   { cvt4_body(w_qkv, wqkvb, i, 384);  return; }
    if ((i -= 110592) < 36864)        { cvt4_body(w_proj, wprojb, i, 384); return; }
    if ((i -= 36864) < 73728)         { cvt4_body(mlp_w1, w1b, i, 384);   return; }
    if ((i -= 73728) < 73728)         { cvt4_body(mlp_w2, w2b, i, 768);   return; }
    if ((i -= 73728) < 307200)        { Sacc[i] = 0.f;                    return; }
    if ((i -= 307200) < 1327104)      { reord_body(pconv1, w1r, i);       return; }
    if ((i -= 1327104) < 1327104)     { reord_body(pconv2, w2r, i);       return; }
    if ((i -= 1327104) < 1024)        { zp[i] = 0u;                       return; }
    if ((i -= 1024) < 2) {
        if (i == 0 && n_extra >= 1) dout[base]     = (float)Hp[0];
        if (i == 1 && n_extra >= 2) dout[base + 1] = (float)Wp[0];
    }
}
#define PREP_TOTAL (110592 + 36864 + 73728 + 73728 + 307200 + 1327104 + 1327104 + 1024 + 2)

// ---------------------------------------------------------------- LayerNorm over C=384 -> fp8
// 256-thr blocks, 4 waves, one row per wave (removes 1-wave-workgroup occupancy cap).
// SWZ=1: pre-swizzled rows (feeds ACONV=0 GEMM A).  SWZ=0: linear rows (feeds conv1 im2col A).
template<bool SWZ>
__global__ __launch_bounds__(256)
void ln_kernel(const float* __restrict__ xf, const float* __restrict__ g,
               const float* __restrict__ b, u8* __restrict__ out) {
    const int row = blockIdx.x * 4 + (threadIdx.x >> 6);
    const int lane = threadIdx.x & 63;
    const float* xr = xf + (size_t)row * 384;
    float v[6], s = 0.f, s2 = 0.f;
#pragma unroll
    for (int i = 0; i < 6; ++i) { v[i] = xr[lane + i * 64]; s += v[i]; s2 += v[i] * v[i]; }
#pragma unroll
    for (int off = 32; off; off >>= 1) { s += __shfl_xor(s, off); s2 += __shfl_xor(s2, off); }
    float mean = s * (1.0f / 384.0f);
    float var  = s2 * (1.0f / 384.0f) - mean * mean;
    float rstd = rsqrtf(var + LN_EPS);
    u8* orow = out + (size_t)row * 384;
    int pofs = lane;
    if (SWZ) {
        const int gperm = (row >> 1) & 7;
        pofs = ((((lane >> 3) + gperm) & 7) << 3) | (lane & 7);
    }
#pragma unroll
    for (int i = 0; i < 6; ++i) {
        int c = lane + i * 64;
        orow[i * 64 + pofs] = f2e4((v[i] - mean) * rstd * g[c] + b[c]);
    }
}

// ---------------------------------------------------------------- MFMA NT GEMM (fp8 e4m3 A,B): C = A[M,K] * B[N,K]^T
// 128x128 tile, BK=64, 256 thr / 4 waves (64x64/wave), dbuf LDS 32 KB -> 4 blk/CU.
// B operand + plain-A: GLOBALLY pre-swizzled (swz) -> linear staging + 8-slot read = ZERO
// bank conflicts (r7-verified). Conv A (im2col, rows shift per tap): LDS-LOCAL 4-chunk
// rotation -- keyed by LDS row, tap-invariant, NO in-loop read recompute (r7 lesson);
// residual 2-way b64 conflict on A only (r8: 5.97e6, ~10%).
// Sync = r2's proven minimal loop: {mfma; lgkm0; bar; STAGE(t+2); counted vmcnt(4); bar}.
// T5 setprio around MFMA cluster: 4 co-resident blocks at different K-steps = role diversity.
// ACONV: 0 plain A[M,K] (pre-swizzled); 1 implicit im2col (H=W=48, K=3456, linear source).
// EPI: 0 bf16 store; 1 BN+GELU->fp8 (SWZO: pre-swizzled vs linear); 2 BN -> xf += gamma*v;
//      3 xf += gamma*v; 4 ofb = xf + gamma*v; 5 xf = xin + gamma*v
template<int ACONV, int EPI, bool SWZO = false>
__global__ __launch_bounds__(256, 4)
void gemm_nt(const u8* __restrict__ A, const u8* __restrict__ Bm,
             int M, int N, int K,
             u16* __restrict__ Obf, int ldo,
             float* __restrict__ xf, float* __restrict__ ofb, const float* __restrict__ xin,
             const float* __restrict__ bn_g, const float* __restrict__ bn_b,
             const float* __restrict__ bn_m, const float* __restrict__ bn_v,
             const float* __restrict__ gamma, const u8* __restrict__ zp) {
    __shared__ u8 As[2][128 * 64];
    __shared__ u8 Bs[2][128 * 64];

    const int tid = threadIdx.x;
    // XCD swizzle: L = (g%8)*(G/8) + g/8 ; n_tile = L % gx (fast), m_tile = L / gx
    const int gx = gridDim.x;
    const int g  = blockIdx.y * gx + blockIdx.x;
    const int G  = gx * gridDim.y;
    int L = g;
    if ((G & 7) == 0) L = (g & 7) * (G >> 3) + (g >> 3);
    const int n0 = (L % gx) * 128;
    const int m0 = (L / gx) * 128;

    const int lane  = tid & 63;
    const int wave  = tid >> 6;
    const int wm    = (wave >> 1) * 64;
    const int wn    = (wave & 1) * 64;
    const int fr    = lane & 15;
    const int klane = lane >> 4;

    int arow[4], brow[4];
#pragma unroll
    for (int i = 0; i < 4; ++i) {
        arow[i] = (wm + i * 16 + fr) * 64;
        brow[i] = (wn + i * 16 + fr) * 64;
    }
    // 8-slot pre-swizzle read (B always; A when ACONV=0): slot = (kh*4 + klane + fr>>1) & 7
    int csw8[2];
#pragma unroll
    for (int kh = 0; kh < 2; ++kh)
        csw8[kh] = ((((kh << 2) + klane) + (fr >> 1)) & 7) << 3;
    // 4-chunk LDS-local rotation read (conv A): chunk = (kh*2 + klane>>1 + fr>>1) & 3
    int csw4[2];
#pragma unroll
    for (int kh = 0; kh < 2; ++kh)
        csw4[kh] = ((((kh << 1) + (klane >> 1) + (fr >> 1)) & 3) << 4) + ((klane & 1) << 3);

    // staging: thread stages 16 B at LDS row (q*64 + tid>>2), phys chunk (tid&3)
    const int srow = tid >> 2;
    const int scol = (tid & 3) << 4;                                  // linear (pre-swizzled src)
    const int ssc4 = ((((tid & 3) - ((tid >> 3) & 3)) & 3) << 4);     // rotation src (conv A)
    const u8 *sa[2], *sb[2];
    const u8* imgq[2];
    int ay[2], ax[2];
#pragma unroll
    for (int q = 0; q < 2; ++q) {
        int r = q * 64 + srow;
        if (ACONV == 0) {
            sa[q] = A + (size_t)(m0 + r) * K + scol;
        } else {
            int nA = m0 + r;
            int bi = nA / 2304;                  // 128-tile never crosses image (128 | 2304)
            int nl = nA - bi * 2304;
            ay[q] = nl / 48;
            ax[q] = nl - ay[q] * 48;
            imgq[q] = A + (size_t)bi * 2304 * 384;
        }
        sb[q] = Bm + (size_t)(n0 + q * 64 + srow) * K + scol;
    }

    int scnt = 0, sjj = 0;
    const int NT = K / 64;

    auto STAGE = [&](int d) {
        if (ACONV == 1) {
            if (scnt == 0) {                     // new 3x3 tap: recompute A pointers
                int t3 = sjj / 3;
                int dy = t3 - 1, dx = sjj - t3 * 3 - 1;
                ++sjj;
#pragma unroll
                for (int q = 0; q < 2; ++q) {
                    int yy = ay[q] + dy, xx = ax[q] + dx;
                    bool v = ((unsigned)yy < 48u) & ((unsigned)xx < 48u);
                    sa[q] = (v ? imgq[q] + (size_t)(yy * 48 + xx) * 384 : zp) + ssc4;
                }
            }
            scnt = (scnt == 5) ? 0 : scnt + 1;
        }
        u8* la = &As[d][0];
        u8* lb = &Bs[d][0];
        gl_lds16(sa[0], la + ((wave * 64) << 4));        sa[0] += 64;
        gl_lds16(sa[1], la + ((256 + wave * 64) << 4));  sa[1] += 64;
        gl_lds16(sb[0], lb + ((wave * 64) << 4));        sb[0] += 64;
        gl_lds16(sb[1], lb + ((256 + wave * 64) << 4));  sb[1] += 64;
    };

    floatx4 acc[4][4];
#pragma unroll
    for (int i = 0; i < 4; ++i)
#pragma unroll
        for (int j = 0; j < 4; ++j) acc[i][j] = (floatx4){0.f, 0.f, 0.f, 0.f};

    // prologue: tiles 0,1 in flight (4 loads each per thread); counted wait on tile 0 only
    STAGE(0);
    STAGE(1);
    asm volatile("s_waitcnt vmcnt(4)" ::: "memory");
    __builtin_amdgcn_s_barrier();
    asm volatile("" ::: "memory");

    int cur = 0;
    for (int t = 0; t < NT; ++t) {
        const u8* Ab = &As[cur][0];
        const u8* Bb = &Bs[cur][0];
#pragma unroll
        for (int kh = 0; kh < 2; ++kh) {
            long af[4], bfr[4];
#pragma unroll
            for (int i = 0; i < 4; ++i) af[i]  = *(const long*)(Ab + arow[i] + (ACONV ? csw4[kh] : csw8[kh]));
#pragma unroll
            for (int j = 0; j < 4; ++j)  bfr[j] = *(const long*)(Bb + brow[j] + csw8[kh]);
            __builtin_amdgcn_s_setprio(1);
#pragma unroll
            for (int i = 0; i < 4; ++i)
#pragma unroll
                for (int j = 0; j < 4; ++j)
                    acc[i][j] = __builtin_amdgcn_mfma_f32_16x16x32_fp8_fp8(af[i], bfr[j], acc[i][j], 0, 0, 0);
            __builtin_amdgcn_s_setprio(0);
        }
        asm volatile("s_waitcnt lgkmcnt(0)" ::: "memory");   // this wave's reads of buf[cur] done
        __builtin_amdgcn_s_barrier();                        // all waves done -> buf[cur] free
        asm volatile("" ::: "memory");
        if (t + 2 < NT) {
            STAGE(cur);                                      // issue tile t+2 into freed buffer
            asm volatile("s_waitcnt vmcnt(4)" ::: "memory"); // drain tile t+1 (issued 1 tile ago)
        } else {
            asm volatile("s_waitcnt vmcnt(0)" ::: "memory"); // tail: nothing new issued
        }
        __builtin_amdgcn_sched_barrier(0);
        __builtin_amdgcn_s_barrier();                        // tile t+1 resident for all waves
        asm volatile("" ::: "memory");
        cur ^= 1;
    }

    // Epilogue. C/D layout: col = lane&15, row = (lane>>4)*4 + reg  [dtype-independent, m121-128]
    const int quad4 = (lane >> 4) * 4;
#pragma unroll
    for (int j = 0; j < 4; ++j) {
        int col = n0 + wn + j * 16 + fr;
        float bscale = 0.f, bshift = 0.f, gam = 0.f;
        if (EPI == 1 || EPI == 2) {
            bscale = bn_g[col] * rsqrtf(bn_v[col] + LN_EPS);
            bshift = bn_b[col] - bn_m[col] * bscale;
        }
        if (EPI >= 2) gam = gamma[col];
#pragma unroll
        for (int i = 0; i < 4; ++i) {
#pragma unroll
            for (int r = 0; r < 4; ++r) {
                int row = m0 + wm + i * 16 + quad4 + r;
                float v = acc[i][j][r];
                if (EPI == 0) {
                    Obf[(size_t)row * ldo + col] = f2bf(v);
                } else if (EPI == 1) {
                    float t = v * bscale + bshift;
                    t = 0.5f * t * (1.0f + erff(t * 0.70710678118654752f));
                    int oc = SWZO ? swz(row, col) : col;
                    ((u8*)Obf)[(size_t)row * ldo + oc] = f2e4(t);
                } else if (EPI == 2) {
                    float t = v * bscale + bshift;
                    xf[(size_t)row * N + col] += gam * t;
                } else if (EPI == 3) {
                    xf[(size_t)row * N + col] += gam * v;
                } else if (EPI == 4) {
                    ofb[(size_t)row * N + col] = xf[(size_t)row * N + col] + gam * v;
                } else {
                    xf[(size_t)row * N + col] = xin[(size_t)row * N + col] + gam * v;
                }
            }
        }
    }
}

// ---------------------------------------------------------------- channel attention, stage 1:
// partial Gram + partial norms over a 128-row N-slice; atomicAdd into f32 accumulators.
// grid (18 slices, 128 bh). qkv stays bf16 (EPI=0 output, NOT swizzled).
__global__ __launch_bounds__(256)
void gram_kernel(const u16* __restrict__ qkv, float* __restrict__ Sacc,
                 float* __restrict__ nrm2) {
    const int bh = blockIdx.y;
    const int b = bh >> 3, h = bh & 7;
    const int tid = threadIdx.x;
    __shared__ float qsf[64][48];
    __shared__ float ksf[64][48];

    float acc9[3][3];
#pragma unroll
    for (int i = 0; i < 3; ++i)
#pragma unroll
        for (int j = 0; j < 3; ++j) acc9[i][j] = 0.f;
    float qn2 = 0.f, kn2 = 0.f;

    const int qoff = h * 48;
    const int koff = 384 + h * 48;
    const int d0 = (tid >> 4) * 3;
    const int e0 = (tid & 15) * 3;
    const int nbase = blockIdx.x * 128;

    for (int c = 0; c < 2; ++c) {
        const int n0 = nbase + c * 64;
#pragma unroll
        for (int it = 0; it < 6; ++it) {
            int chunk = tid + it * 256;          // 0..1535: [q 768 | k 768] chunks of 4 bf16
            int mat = chunk >= 768 ? 1 : 0;
            int rem = chunk - mat * 768;
            int nn = rem / 12, u = rem - nn * 12;
            ushort4 raw = *(const ushort4*)(qkv + (size_t)(b * 2304 + n0 + nn) * 1152 +
                                            (mat ? koff : qoff) + u * 4);
            float4 f = make_float4(bf2f(raw.x), bf2f(raw.y), bf2f(raw.z), bf2f(raw.w));
            if (mat) *(float4*)&ksf[nn][u * 4] = f;
            else     *(float4*)&qsf[nn][u * 4] = f;
        }
        __syncthreads();
#pragma unroll 4
        for (int nn = 0; nn < 64; ++nn) {
            float q0 = qsf[nn][d0], q1 = qsf[nn][d0 + 1], q2 = qsf[nn][d0 + 2];
            float k0v = ksf[nn][e0], k1v = ksf[nn][e0 + 1], k2v = ksf[nn][e0 + 2];
            acc9[0][0] += q0 * k0v; acc9[0][1] += q0 * k1v; acc9[0][2] += q0 * k2v;
            acc9[1][0] += q1 * k0v; acc9[1][1] += q1 * k1v; acc9[1][2] += q1 * k2v;
            acc9[2][0] += q2 * k0v; acc9[2][1] += q2 * k1v; acc9[2][2] += q2 * k2v;
        }
        if (tid < 48) {
            for (int nn = 0; nn < 64; ++nn) { float q = qsf[nn][tid]; qn2 += q * q; }
        } else if (tid >= 128 && tid < 176) {
            int e = tid - 128;
            for (int nn = 0; nn < 64; ++nn) { float k = ksf[nn][e]; kn2 += k * k; }
        }
        __syncthreads();
    }

    float* Sb = Sacc + (size_t)bh * 2304;
#pragma unroll
    for (int i = 0; i < 3; ++i)
#pragma unroll
        for (int j = 0; j < 3; ++j)
            atomicAdd(&Sb[(d0 + i) * 48 + e0 + j], acc9[i][j]);
    if (tid < 48) atomicAdd(&nrm2[bh * 96 + tid], qn2);
    else if (tid >= 128 && tid < 176) atomicAdd(&nrm2[bh * 96 + 48 + (tid - 128)], kn2);
}

// ---------------------------------------------------------------- channel attention, stage 2
__global__ __launch_bounds__(256)
void attn_fin_kernel(const float* __restrict__ Sacc, const float* __restrict__ nrm2,
                     const float* __restrict__ temp, float* __restrict__ attnb) {
    const int bh = blockIdx.x;
    const int h = bh & 7;
    const int tid = threadIdx.x;
    __shared__ float S[48][49];
    __shared__ float qns[48], kns[48];

    const float* Sb = Sacc + (size_t)bh * 2304;
    for (int i = tid; i < 2304; i += 256) {
        int d = i / 48, e = i - d * 48;
        S[d][e] = Sb[i];
    }
    if (tid < 48)      qns[tid]      = fmaxf(sqrtf(nrm2[bh * 96 + tid]), 1e-12f);
    else if (tid < 96) kns[tid - 48] = fmaxf(sqrtf(nrm2[bh * 96 + tid]), 1e-12f);
    __syncthreads();

    if (tid < 48) {
        float tf = temp[h] / qns[tid];
        float mx = -1e30f;
        for (int e = 0; e < 48; ++e) {
            float t = S[tid][e] * tf / kns[e];
            S[tid][e] = t;
            mx = fmaxf(mx, t);
        }
        float sum = 0.f;
        for (int e = 0; e < 48; ++e) { float t = __expf(S[tid][e] - mx); S[tid][e] = t; sum += t; }
        float inv = 1.0f / sum;
        float* dst = attnb + ((size_t)bh * 48 + tid) * 48;
        for (int e = 0; e < 48; ++e) dst[e] = S[tid][e] * inv;
    }
}

// ---------------------------------------------------------------- out[b,n,h*48+d] = sum_e attn[b,h,d,e] * v[b,n,h*48+e]
// writes z as fp8, PRE-SWIZZLED (feeds proj GEMM-A, ACONV=0)
__global__ __launch_bounds__(256)
void attnout_kernel(const u16* __restrict__ qkv, const float* __restrict__ attnb,
                    u8* __restrict__ z) {
    const int r0 = blockIdx.x * 64;
    const int h  = blockIdx.y;
    const int b  = r0 / 2304;
    const int tid = threadIdx.x;
    __shared__ float A[48][49];
    __shared__ float vsf[64][48];

    const float* asrc = attnb + (size_t)(b * 8 + h) * 2304;
    for (int i = tid; i < 2304; i += 256) {
        int d = i / 48, e = i - d * 48;
        A[d][e] = asrc[i];
    }
    const int voff = 768 + h * 48;
    for (int i = tid; i < 768; i += 256) {
        int nn = i / 12, u = i - nn * 12;
        ushort4 raw = *(const ushort4*)(qkv + (size_t)(r0 + nn) * 1152 + voff + u * 4);
        float4 f = make_float4(bf2f(raw.x), bf2f(raw.y), bf2f(raw.z), bf2f(raw.w));
        *(float4*)&vsf[nn][u * 4] = f;
    }
    __syncthreads();

    const int rr0 = (tid >> 4) * 4;
    const int d0  = (tid & 15) * 3;
    float acc[4][3];
#pragma unroll
    for (int r = 0; r < 4; ++r)
#pragma unroll
        for (int j = 0; j < 3; ++j) acc[r][j] = 0.f;

#pragma unroll 4
    for (int e = 0; e < 48; ++e) {
        float a0 = A[d0][e], a1 = A[d0 + 1][e], a2 = A[d0 + 2][e];
#pragma unroll
        for (int r = 0; r < 4; ++r) {
            float vv = vsf[rr0 + r][e];
            acc[r][0] += a0 * vv; acc[r][1] += a1 * vv; acc[r][2] += a2 * vv;
        }
    }
#pragma unroll
    for (int r = 0; r < 4; ++r)
#pragma unroll
        for (int j = 0; j < 3; ++j) {
            int row = r0 + rr0 + r;
            int col = h * 48 + d0 + j;
            z[(size_t)row * 384 + swz(row, col)] = f2e4(acc[r][j]);
        }
}

extern "C" void kernel_launch(void* const* d_in, const int* in_sizes, int n_in,
                              void* d_out, int out_size, void* d_ws, size_t ws_size,
                              hipStream_t stream) {
    const float* x      = (const float*)d_in[0];
    const float* ln1_g  = (const float*)d_in[1];
    const float* ln1_b  = (const float*)d_in[2];
    const float* w_qkv  = (const float*)d_in[3];
    const float* temp   = (const float*)d_in[4];
    const float* w_proj = (const float*)d_in[5];
    const float* gamma1 = (const float*)d_in[6];
    const float* ln2_g  = (const float*)d_in[7];
    const float* ln2_b  = (const float*)d_in[8];
    const float* mlp_w1 = (const float*)d_in[9];
    const float* bn1_g  = (const float*)d_in[10];
    const float* bn1_b  = (const float*)d_in[11];
    const float* bn1_m  = (const float*)d_in[12];
    const float* bn1_v  = (const float*)d_in[13];
    const float* mlp_w2 = (const float*)d_in[14];
    const float* bn2_g  = (const float*)d_in[15];
    const float* bn2_b  = (const float*)d_in[16];
    const float* bn2_m  = (const float*)d_in[17];
    const float* bn2_v  = (const float*)d_in[18];
    const float* gamma2 = (const float*)d_in[19];
    const float* ln3_g  = (const float*)d_in[20];
    const float* ln3_b  = (const float*)d_in[21];
    const float* pconv1 = (const float*)d_in[22];
    const float* pbn_g  = (const float*)d_in[23];
    const float* pbn_b  = (const float*)d_in[24];
    const float* pbn_m  = (const float*)d_in[25];
    const float* pbn_v  = (const float*)d_in[26];
    const float* pconv2 = (const float*)d_in[27];
    const float* gamma3 = (const float*)d_in[28];
    const int* Hp = (const int*)d_in[29];
    const int* Wp = (const int*)d_in[30];

    const int M = 36864, C = 384, C2 = 768, NQKV = 1152, KC = 3456;
    const size_t NBNC = (size_t)M * C;                 // 14,155,776

    const size_t SZ_XF  = NBNC * 4;                    //  f32 residual stream
    const size_t SZ_LN  = NBNC * 2;                    //  fp8 LN out / z (half used)
    const size_t SZ_BIG = (size_t)M * NQKV * 2;        //  bf16 qkv / fp8 mlp hidden
    const size_t SZ_P3  = SZ_LN;                       //  attnb + weights + Gram accum, later conv1 out
    const size_t SZ_W   = (size_t)C * KC * 2;
    if (ws_size < SZ_XF + SZ_LN + SZ_BIG + SZ_P3 + 2 * SZ_W + 4096) return;

    char* ws = (char*)d_ws;
    float* xf     = (float*)ws;
    u8*    lnbuf  = (u8*)(ws + SZ_XF);
    u16*   big    = (u16*)(ws + SZ_XF + SZ_LN);
    char*  p3     = ws + SZ_XF + SZ_LN + SZ_BIG;
    float* attnb  = (float*)p3;                                      // 1,179,648 B
    u8*    wqkvb  = (u8*)(p3 + 1179648);
    u8*    wprojb = (u8*)(p3 + 1179648 + 884736);
    u8*    w1b    = (u8*)(p3 + 1179648 + 884736 + 294912);
    u8*    w2b    = (u8*)(p3 + 1179648 + 884736 + 294912 + 589824);
    float* Sacc   = (float*)(p3 + 3538944);                          // 128*2304 f32
    float* nrm2   = (float*)(p3 + 3538944 + 1179648);                // 128*96 f32 (contiguous)
    u8*    convbf = (u8*)p3;                                         // conv1 output (fp8, M*C), block 3 only
    u8*    w1r    = (u8*)(p3 + SZ_P3);
    u8*    w2r    = (u8*)(p3 + SZ_P3 + SZ_W);
    u8*    zpg    = (u8*)(p3 + SZ_P3 + 2 * SZ_W);                    // dedicated 4 KB zero page

    const int n_extra = out_size - (int)NBNC;

    // merged prep: all weight cvt/reorder + accumulator zero + zero page + H/W tail (1 launch)
    prep_kernel<<<(PREP_TOTAL + 255) / 256, 256, 0, stream>>>(
        w_qkv, wqkvb, w_proj, wprojb, mlp_w1, w1b, mlp_w2, w2b,
        Sacc, pconv1, w1r, pconv2, w2r, (unsigned int*)zpg,
        Hp, Wp, (float*)d_out, NBNC, n_extra);

    // --- attention block ---  (ln1 reads input x directly)
    ln_kernel<true><<<M / 4, 256, 0, stream>>>(x, ln1_g, ln1_b, lnbuf);
    gemm_nt<0, 0><<<dim3(NQKV / 128, M / 128), 256, 0, stream>>>(
        lnbuf, wqkvb, M, NQKV, C, big, NQKV, nullptr, nullptr, nullptr,
        nullptr, nullptr, nullptr, nullptr, nullptr, nullptr);
    gram_kernel<<<dim3(18, 128), 256, 0, stream>>>(big, Sacc, nrm2);
    attn_fin_kernel<<<128, 256, 0, stream>>>(Sacc, nrm2, temp, attnb);
    attnout_kernel<<<dim3(M / 64, 8), 256, 0, stream>>>(big, attnb, lnbuf);
    gemm_nt<0, 5><<<dim3(C / 128, M / 128), 256, 0, stream>>>(        // xf = x + gamma1 * proj
        lnbuf, wprojb, M, C, C, nullptr, 0, xf, nullptr, x,
        nullptr, nullptr, nullptr, nullptr, gamma1, nullptr);

    // --- ConvMlp block (1x1 convs + eval BN) ---
    ln_kernel<true><<<M / 4, 256, 0, stream>>>(xf, ln2_g, ln2_b, lnbuf);
    gemm_nt<0, 1, true><<<dim3(C2 / 128, M / 128), 256, 0, stream>>>(
        lnbuf, w1b, M, C2, C, (u16*)big, C2, nullptr, nullptr, nullptr,
        bn1_g, bn1_b, bn1_m, bn1_v, nullptr, nullptr);
    gemm_nt<0, 2><<<dim3(C / 128, M / 128), 256, 0, stream>>>(
        (u8*)big, w2b, M, C, C2, nullptr, 0, xf, nullptr, nullptr,
        bn2_g, bn2_b, bn2_m, bn2_v, gamma2, nullptr);

    // --- projection block (3x3 conv -> BN -> GELU -> 3x3 conv), implicit im2col GEMMs ---
    ln_kernel<false><<<M / 4, 256, 0, stream>>>(xf, ln3_g, ln3_b, lnbuf);   // linear (conv A source)
    gemm_nt<1, 1, false><<<dim3(C / 128, M / 128), 256, 0, stream>>>(  // convbf linear (conv2 A source)
        lnbuf, w1r, M, C, KC, (u16*)convbf, C, nullptr, nullptr, nullptr,
        pbn_g, pbn_b, pbn_m, pbn_v, nullptr, zpg);
    gemm_nt<1, 4><<<dim3(C / 128, M / 128), 256, 0, stream>>>(
        convbf, w2r, M, C, KC, nullptr, 0, xf, (float*)d_out, nullptr,
        nullptr, nullptr, nullptr, nullptr, gamma3, zpg);
}